// Round 1
// 1063.862 us; speedup vs baseline: 2.5634x; 2.5634x over previous
//
#include <hip/hip_runtime.h>

#define D 64
#define H 128

__device__ __forceinline__ float wave_sum(float v) {
#pragma unroll
  for (int off = 32; off > 0; off >>= 1) v += __shfl_xor(v, off, 64);
  return v;
}

// ---------------- CSR build ----------------
__global__ __launch_bounds__(256) void k_hist(const int* __restrict__ dst,
                                              int* __restrict__ cnt, int E) {
  int e = blockIdx.x * 256 + threadIdx.x;
  if (e < E) atomicAdd(cnt + dst[e], 1);
}

__global__ __launch_bounds__(256) void k_alloc(const int* __restrict__ cnt,
                                               int* __restrict__ offs,
                                               int* __restrict__ cursor,
                                               int* __restrict__ total, int N) {
  int n = blockIdx.x * 256 + threadIdx.x;
  int lane = threadIdx.x & 63;
  int c = (n < N) ? cnt[n] : 0;
  int incl = c;
#pragma unroll
  for (int off = 1; off < 64; off <<= 1) {
    int t = __shfl_up(incl, off, 64);
    if (lane >= off) incl += t;
  }
  int base = 0;
  if (lane == 63) base = atomicAdd(total, incl);
  base = __shfl(base, 63, 64);
  if (n < N) {
    int o = base + incl - c;
    offs[n] = o;
    cursor[n] = o;
  }
}

__global__ __launch_bounds__(256) void k_bin(const int* __restrict__ src,
                                             const int* __restrict__ dst,
                                             int* __restrict__ cursor,
                                             int2* __restrict__ csr, int E) {
  int e = blockIdx.x * 256 + threadIdx.x;
  if (e >= E) return;
  int d = dst[e];
  int pos = atomicAdd(cursor + d, 1);
  csr[pos] = make_int2(e, src[e]);
}

// ---------------- aggregate + combine: wave per node, lane = feature --------
__global__ __launch_bounds__(256) void k_agg(
    const float* __restrict__ node, const float* __restrict__ edge,
    const int2* __restrict__ csr, const int* __restrict__ offs,
    const int* __restrict__ cnt, const float* __restrict__ epsp,
    float* __restrict__ h, int N)
{
  int wid = (blockIdx.x * 256 + threadIdx.x) >> 6;
  int lane = threadIdx.x & 63;
  if (wid >= N) return;
  int start = offs[wid];
  int c = cnt[wid];
  float acc = 0.0f;
  for (int i = 0; i < c; ++i) {
    int2 p = csr[start + i];
    acc += edge[(size_t)p.x * D + lane] + node[(size_t)p.y * D + lane];
  }
  float inv = (c > 0) ? (1.0f / (float)c) : 0.0f;
  float hv = fmaf(1.0f + epsp[0], node[(size_t)wid * D + lane], acc * inv);
  h[(size_t)wid * D + lane] = hv;
}

// ---------------- GEMM1 + bias + BN1 stats (LDS-tiled) ----------------
// tile: 64 rows x 128 cols, 256 threads, thread = 8 rows x 4 cols
__global__ __launch_bounds__(256) void k_gemm1(
    const float* __restrict__ h, const float* __restrict__ W1,
    const float* __restrict__ b1, float* __restrict__ h1,
    float* __restrict__ sum1, float* __restrict__ sq1, int N)
{
  __shared__ float sW[D][H];      // 32 KB  W1 copy [k][c]
  __shared__ float sX[64][D];     // 16 KB  h tile  [r][k]
  __shared__ float sSum[H], sSq[H];

  const int t = threadIdx.x;
  const int row0 = blockIdx.x * 64;

  // stage W1: 8192 floats, 8 float4/thread, contiguous
  {
    const float4* gW = (const float4*)W1;
    float4* sWv = (float4*)&sW[0][0];
#pragma unroll
    for (int q = 0; q < 8; ++q) sWv[q * 256 + t] = gW[q * 256 + t];
  }
  // stage h tile: 4096 floats, 4 float4/thread; zero-pad tail rows
  {
    float4* sXv = (float4*)&sX[0][0];
#pragma unroll
    for (int q = 0; q < 4; ++q) {
      int idx = q * 256 + t;          // float4 idx: row = idx>>4, col4 = idx&15
      int r = idx >> 4;
      int gr = row0 + r;
      float4 v = make_float4(0.f, 0.f, 0.f, 0.f);
      if (gr < N) v = *(const float4*)(h + (size_t)gr * D + (idx & 15) * 4);
      sXv[idx] = v;
    }
  }
  if (t < H) { sSum[t] = 0.f; sSq[t] = 0.f; }
  __syncthreads();

  const int rg = t >> 5;   // 0..7   (8 rows each)
  const int cg = t & 31;   // 0..31  (4 cols each)
  const int r0 = rg * 8;
  const int c0 = cg * 4;

  float acc[8][4];
#pragma unroll
  for (int i = 0; i < 8; ++i)
#pragma unroll
    for (int j = 0; j < 4; ++j) acc[i][j] = 0.f;

  for (int k = 0; k < D; k += 4) {
    float4 xv[8], wv[4];
#pragma unroll
    for (int i = 0; i < 8; ++i) xv[i] = *(const float4*)&sX[r0 + i][k];
#pragma unroll
    for (int kk = 0; kk < 4; ++kk) wv[kk] = *(const float4*)&sW[k + kk][c0];
#pragma unroll
    for (int kk = 0; kk < 4; ++kk) {
      const float* wp = (const float*)&wv[kk];
#pragma unroll
      for (int i = 0; i < 8; ++i) {
        const float xs = ((const float*)&xv[i])[kk];
        acc[i][0] = fmaf(xs, wp[0], acc[i][0]);
        acc[i][1] = fmaf(xs, wp[1], acc[i][1]);
        acc[i][2] = fmaf(xs, wp[2], acc[i][2]);
        acc[i][3] = fmaf(xs, wp[3], acc[i][3]);
      }
    }
  }

  const float4 bv = *(const float4*)(b1 + c0);
  float ls0 = 0.f, ls1 = 0.f, ls2 = 0.f, ls3 = 0.f;
  float lq0 = 0.f, lq1 = 0.f, lq2 = 0.f, lq3 = 0.f;
#pragma unroll
  for (int i = 0; i < 8; ++i) {
    int gr = row0 + r0 + i;
    if (gr < N) {
      float o0 = acc[i][0] + bv.x, o1 = acc[i][1] + bv.y;
      float o2 = acc[i][2] + bv.z, o3 = acc[i][3] + bv.w;
      *(float4*)(h1 + (size_t)gr * H + c0) = make_float4(o0, o1, o2, o3);
      ls0 += o0; lq0 += o0 * o0;
      ls1 += o1; lq1 += o1 * o1;
      ls2 += o2; lq2 += o2 * o2;
      ls3 += o3; lq3 += o3 * o3;
    }
  }
  // combine the two row-groups sharing this wave, then LDS-reduce
  ls0 += __shfl_xor(ls0, 32, 64); lq0 += __shfl_xor(lq0, 32, 64);
  ls1 += __shfl_xor(ls1, 32, 64); lq1 += __shfl_xor(lq1, 32, 64);
  ls2 += __shfl_xor(ls2, 32, 64); lq2 += __shfl_xor(lq2, 32, 64);
  ls3 += __shfl_xor(ls3, 32, 64); lq3 += __shfl_xor(lq3, 32, 64);
  if (!(t & 32)) {
    atomicAdd(&sSum[c0 + 0], ls0); atomicAdd(&sSq[c0 + 0], lq0);
    atomicAdd(&sSum[c0 + 1], ls1); atomicAdd(&sSq[c0 + 1], lq1);
    atomicAdd(&sSum[c0 + 2], ls2); atomicAdd(&sSq[c0 + 2], lq2);
    atomicAdd(&sSum[c0 + 3], ls3); atomicAdd(&sSq[c0 + 3], lq3);
  }
  __syncthreads();
  if (t < H) { atomicAdd(sum1 + t, sSum[t]); atomicAdd(sq1 + t, sSq[t]); }
}

// ---------------- BN finalize -----------------------
__global__ void k_finalize(const float* __restrict__ sum, const float* __restrict__ sq,
                           const float* __restrict__ gamma, const float* __restrict__ beta,
                           float* __restrict__ scale, float* __restrict__ shift,
                           int C, float invN)
{
  int k = threadIdx.x;
  if (k < C) {
    float m = sum[k] * invN;
    float var = fmaf(-m, m, sq[k] * invN);
    float sc = gamma[k] * rsqrtf(var + 1e-5f);
    scale[k] = sc;
    shift[k] = fmaf(-m, sc, beta[k]);
  }
}

// ---------------- BN1+ReLU + GEMM2 + bias + BN2 stats (LDS-tiled) -----------
// tile: 64 rows x 64 cols, 256 threads, thread = 4 rows x 4 cols
__global__ __launch_bounds__(256) void k_gemm2(
    const float* __restrict__ h1, const float* __restrict__ scale1,
    const float* __restrict__ shift1, const float* __restrict__ W2,
    const float* __restrict__ b2, float* __restrict__ out,
    float* __restrict__ sum2, float* __restrict__ sq2, int N)
{
  __shared__ float sW[H][D];          // 32 KB  W2 copy [k][c]
  __shared__ float sX[64][H + 4];     // 33 KB  relu(bn1(h1)) tile, padded
  __shared__ float sSum[D], sSq[D];

  const int t = threadIdx.x;
  const int row0 = blockIdx.x * 64;

  // stage W2: 8192 floats, 8 float4/thread
  {
    const float4* gW = (const float4*)W2;
    float4* sWv = (float4*)&sW[0][0];
#pragma unroll
    for (int q = 0; q < 8; ++q) sWv[q * 256 + t] = gW[q * 256 + t];
  }
  // stage A tile with BN1+ReLU fused: 8192 floats, 8 float4/thread
#pragma unroll
  for (int q = 0; q < 8; ++q) {
    int idx = q * 256 + t;             // float4 idx: row = idx>>5, k4 = (idx&31)*4
    int r = idx >> 5;
    int k4 = (idx & 31) * 4;
    int gr = row0 + r;
    float4 x = make_float4(0.f, 0.f, 0.f, 0.f);
    if (gr < N) {
      float4 v  = *(const float4*)(h1 + (size_t)gr * H + k4);
      float4 sc = *(const float4*)(scale1 + k4);
      float4 sh = *(const float4*)(shift1 + k4);
      x.x = fmaxf(fmaf(v.x, sc.x, sh.x), 0.f);
      x.y = fmaxf(fmaf(v.y, sc.y, sh.y), 0.f);
      x.z = fmaxf(fmaf(v.z, sc.z, sh.z), 0.f);
      x.w = fmaxf(fmaf(v.w, sc.w, sh.w), 0.f);
    }
    *(float4*)&sX[r][k4] = x;
  }
  if (t < D) { sSum[t] = 0.f; sSq[t] = 0.f; }
  __syncthreads();

  const int rg = t >> 4;   // 0..15  (4 rows each)
  const int cg = t & 15;   // 0..15  (4 cols each)
  const int r0 = rg * 4;
  const int c0 = cg * 4;

  float acc[4][4];
#pragma unroll
  for (int i = 0; i < 4; ++i)
#pragma unroll
    for (int j = 0; j < 4; ++j) acc[i][j] = 0.f;

  for (int k = 0; k < H; k += 4) {
    float4 xv[4], wv[4];
#pragma unroll
    for (int i = 0; i < 4; ++i) xv[i] = *(const float4*)&sX[r0 + i][k];
#pragma unroll
    for (int kk = 0; kk < 4; ++kk) wv[kk] = *(const float4*)&sW[k + kk][c0];
#pragma unroll
    for (int kk = 0; kk < 4; ++kk) {
      const float* wp = (const float*)&wv[kk];
#pragma unroll
      for (int i = 0; i < 4; ++i) {
        const float xs = ((const float*)&xv[i])[kk];
        acc[i][0] = fmaf(xs, wp[0], acc[i][0]);
        acc[i][1] = fmaf(xs, wp[1], acc[i][1]);
        acc[i][2] = fmaf(xs, wp[2], acc[i][2]);
        acc[i][3] = fmaf(xs, wp[3], acc[i][3]);
      }
    }
  }

  const float4 bv = *(const float4*)(b2 + c0);
  float ls[4] = {0.f, 0.f, 0.f, 0.f};
  float lq[4] = {0.f, 0.f, 0.f, 0.f};
#pragma unroll
  for (int i = 0; i < 4; ++i) {
    int gr = row0 + r0 + i;
    if (gr < N) {
      float o0 = acc[i][0] + bv.x, o1 = acc[i][1] + bv.y;
      float o2 = acc[i][2] + bv.z, o3 = acc[i][3] + bv.w;
      *(float4*)(out + (size_t)gr * D + c0) = make_float4(o0, o1, o2, o3);
      ls[0] += o0; lq[0] += o0 * o0;
      ls[1] += o1; lq[1] += o1 * o1;
      ls[2] += o2; lq[2] += o2 * o2;
      ls[3] += o3; lq[3] += o3 * o3;
    }
  }
#pragma unroll
  for (int j = 0; j < 4; ++j) {
    ls[j] += __shfl_xor(ls[j], 16, 64); lq[j] += __shfl_xor(lq[j], 16, 64);
    ls[j] += __shfl_xor(ls[j], 32, 64); lq[j] += __shfl_xor(lq[j], 32, 64);
  }
  if ((t & 48) == 0) {
#pragma unroll
    for (int j = 0; j < 4; ++j) {
      atomicAdd(&sSum[c0 + j], ls[j]);
      atomicAdd(&sSq[c0 + j], lq[j]);
    }
  }
  __syncthreads();
  if (t < D) { atomicAdd(sum2 + t, sSum[t]); atomicAdd(sq2 + t, sSq[t]); }
}

// ---------------- final BN2 + ReLU (in-place on d_out) ------------
__global__ __launch_bounds__(256) void k_bnrelu(
    float* __restrict__ out, const float* __restrict__ scale2,
    const float* __restrict__ shift2, size_t n4)
{
  size_t idx = (size_t)blockIdx.x * 256 + threadIdx.x;
  if (idx >= n4) return;
  int k = (int)((idx * 4) & (D - 1));
  float4 v = *(float4*)(out + idx * 4);
  v.x = fmaxf(fmaf(v.x, scale2[k + 0], shift2[k + 0]), 0.0f);
  v.y = fmaxf(fmaf(v.y, scale2[k + 1], shift2[k + 1]), 0.0f);
  v.z = fmaxf(fmaf(v.z, scale2[k + 2], shift2[k + 2]), 0.0f);
  v.w = fmaxf(fmaf(v.w, scale2[k + 3], shift2[k + 3]), 0.0f);
  *(float4*)(out + idx * 4) = v;
}

extern "C" void kernel_launch(void* const* d_in, const int* in_sizes, int n_in,
                              void* d_out, int out_size, void* d_ws, size_t ws_size,
                              hipStream_t stream)
{
  const float* node   = (const float*)d_in[0];
  const float* edge   = (const float*)d_in[1];
  const int*   src    = (const int*)d_in[2];
  const int*   dst    = (const int*)d_in[3];
  const float* eps    = (const float*)d_in[4];
  const float* W1     = (const float*)d_in[5];
  const float* b1     = (const float*)d_in[6];
  const float* gamma1 = (const float*)d_in[7];
  const float* beta1  = (const float*)d_in[8];
  const float* W2     = (const float*)d_in[9];
  const float* b2     = (const float*)d_in[10];
  const float* gamma2 = (const float*)d_in[11];
  const float* beta2  = (const float*)d_in[12];
  float* out = (float*)d_out;

  const int N = in_sizes[0] / D;
  const int E = in_sizes[2];

  // workspace layout in 4-byte words:
  //   0: sum1(H) 128: sq1(H) 256: sum2(D) 320: sq2(D)
  //   384: scale1(H) 512: shift1(H) 640: scale2(D) 704: shift2(D)
  //   768: total(1) [pad to 832]
  //   832: cnt(N)  832+N: offs(N)  832+2N: cursor(N)
  //   832+3N: h(N*D)
  //   832+3N+N*D: csr(2E) aliased with h1(N*H)  [lifetimes disjoint]
  char* base = (char*)d_ws;
  float* sum1   = (float*)base;
  float* sq1    = sum1 + H;
  float* sum2   = sq1 + H;
  float* sq2    = sum2 + D;
  float* scale1 = sq2 + D;
  float* shift1 = scale1 + H;
  float* scale2 = shift1 + H;
  float* shift2 = scale2 + D;
  int*   total  = (int*)(shift2 + D);          // word 768
  int*   cnt    = (int*)base + 832;
  int*   offs   = cnt + N;
  int*   cursor = offs + N;
  float* h      = (float*)(cursor + N);
  int2*  csr    = (int2*)(h + (size_t)N * D);
  float* h1     = (float*)csr;

  // zero: stats (0..384), total (768), cnt — one contiguous memset of the
  // first 832+N words covers all of them (scale/shift are write-before-read)
  hipMemsetAsync(d_ws, 0, (size_t)(832 + N) * sizeof(int), stream);

  int ebn = (E + 255) / 256;
  int nbn = (N + 255) / 256;
  k_hist<<<ebn, 256, 0, stream>>>(dst, cnt, E);
  k_alloc<<<nbn, 256, 0, stream>>>(cnt, offs, cursor, total, N);
  k_bin<<<ebn, 256, 0, stream>>>(src, dst, cursor, csr, E);
  k_agg<<<(N * 64 + 255) / 256, 256, 0, stream>>>(node, edge, csr, offs, cnt, eps, h, N);

  int gtile = (N + 63) / 64;
  k_gemm1<<<gtile, 256, 0, stream>>>(h, W1, b1, h1, sum1, sq1, N);
  k_finalize<<<1, H, 0, stream>>>(sum1, sq1, gamma1, beta1, scale1, shift1, H, 1.0f / (float)N);
  k_gemm2<<<gtile, 256, 0, stream>>>(h1, scale1, shift1, W2, b2, out, sum2, sq2, N);
  k_finalize<<<1, D, 0, stream>>>(sum2, sq2, gamma2, beta2, scale2, shift2, D, 1.0f / (float)N);

  size_t n4 = (size_t)N * D / 4;
  k_bnrelu<<<(int)((n4 + 255) / 256), 256, 0, stream>>>(out, scale2, shift2, n4);
}

// Round 3
// 931.471 us; speedup vs baseline: 2.9277x; 1.1421x over previous
//
#include <hip/hip_runtime.h>

#define D 64
#define H 128

__device__ __forceinline__ float wave_sum(float v) {
#pragma unroll
  for (int off = 32; off > 0; off >>= 1) v += __shfl_xor(v, off, 64);
  return v;
}

// ---------------- CSR build ----------------
__global__ __launch_bounds__(256) void k_hist(const int* __restrict__ dst,
                                              int* __restrict__ cnt, int E) {
  int e = blockIdx.x * 256 + threadIdx.x;
  if (e < E) atomicAdd(cnt + dst[e], 1);
}

__global__ __launch_bounds__(256) void k_alloc(const int* __restrict__ cnt,
                                               int* __restrict__ offs,
                                               int* __restrict__ cursor,
                                               int* __restrict__ total, int N) {
  int n = blockIdx.x * 256 + threadIdx.x;
  int lane = threadIdx.x & 63;
  int c = (n < N) ? cnt[n] : 0;
  int incl = c;
#pragma unroll
  for (int off = 1; off < 64; off <<= 1) {
    int t = __shfl_up(incl, off, 64);
    if (lane >= off) incl += t;
  }
  int base = 0;
  if (lane == 63) base = atomicAdd(total, incl);
  base = __shfl(base, 63, 64);
  if (n < N) {
    int o = base + incl - c;
    offs[n] = o;
    cursor[n] = o;
  }
}

__global__ __launch_bounds__(256) void k_bin(const int* __restrict__ src,
                                             const int* __restrict__ dst,
                                             int* __restrict__ cursor,
                                             int2* __restrict__ csr, int E) {
  int e = blockIdx.x * 256 + threadIdx.x;
  if (e >= E) return;
  int d = dst[e];
  int pos = atomicAdd(cursor + d, 1);
  csr[pos] = make_int2(e, src[e]);
}

// ---------------- aggregate + combine: wave per node, lane = feature --------
// unroll-8 with batched loads: 8 csr entries then 16 gathers in flight per wave
__global__ __launch_bounds__(256) void k_agg(
    const float* __restrict__ node, const float* __restrict__ edge,
    const int2* __restrict__ csr, const int* __restrict__ offs,
    const int* __restrict__ cnt, const float* __restrict__ epsp,
    float* __restrict__ h, int N)
{
  int wid = (blockIdx.x * 256 + threadIdx.x) >> 6;
  int lane = threadIdx.x & 63;
  if (wid >= N) return;
  int start = offs[wid];
  int c = cnt[wid];
  // csr entry as 8-byte int: low 32 = edge id (x), high 32 = src node (y)
  const long long* p = (const long long*)(csr + start);

  float a0 = 0.f, a1 = 0.f, a2 = 0.f, a3 = 0.f;
  int i = 0;
  for (; i + 8 <= c; i += 8) {
    long long q0 = __builtin_nontemporal_load(p + i + 0);
    long long q1 = __builtin_nontemporal_load(p + i + 1);
    long long q2 = __builtin_nontemporal_load(p + i + 2);
    long long q3 = __builtin_nontemporal_load(p + i + 3);
    long long q4 = __builtin_nontemporal_load(p + i + 4);
    long long q5 = __builtin_nontemporal_load(p + i + 5);
    long long q6 = __builtin_nontemporal_load(p + i + 6);
    long long q7 = __builtin_nontemporal_load(p + i + 7);
    float e0 = __builtin_nontemporal_load(edge + (size_t)(unsigned)(q0) * D + lane);
    float e1 = __builtin_nontemporal_load(edge + (size_t)(unsigned)(q1) * D + lane);
    float e2 = __builtin_nontemporal_load(edge + (size_t)(unsigned)(q2) * D + lane);
    float e3 = __builtin_nontemporal_load(edge + (size_t)(unsigned)(q3) * D + lane);
    float e4 = __builtin_nontemporal_load(edge + (size_t)(unsigned)(q4) * D + lane);
    float e5 = __builtin_nontemporal_load(edge + (size_t)(unsigned)(q5) * D + lane);
    float e6 = __builtin_nontemporal_load(edge + (size_t)(unsigned)(q6) * D + lane);
    float e7 = __builtin_nontemporal_load(edge + (size_t)(unsigned)(q7) * D + lane);
    float n0 = node[(size_t)(unsigned)(q0 >> 32) * D + lane];
    float n1 = node[(size_t)(unsigned)(q1 >> 32) * D + lane];
    float n2 = node[(size_t)(unsigned)(q2 >> 32) * D + lane];
    float n3 = node[(size_t)(unsigned)(q3 >> 32) * D + lane];
    float n4 = node[(size_t)(unsigned)(q4 >> 32) * D + lane];
    float n5 = node[(size_t)(unsigned)(q5 >> 32) * D + lane];
    float n6 = node[(size_t)(unsigned)(q6 >> 32) * D + lane];
    float n7 = node[(size_t)(unsigned)(q7 >> 32) * D + lane];
    a0 += e0 + n0; a1 += e1 + n1; a2 += e2 + n2; a3 += e3 + n3;
    a0 += e4 + n4; a1 += e5 + n5; a2 += e6 + n6; a3 += e7 + n7;
  }
  for (; i + 2 <= c; i += 2) {
    long long q0 = p[i + 0];
    long long q1 = p[i + 1];
    float e0 = __builtin_nontemporal_load(edge + (size_t)(unsigned)(q0) * D + lane);
    float e1 = __builtin_nontemporal_load(edge + (size_t)(unsigned)(q1) * D + lane);
    float n0 = node[(size_t)(unsigned)(q0 >> 32) * D + lane];
    float n1 = node[(size_t)(unsigned)(q1 >> 32) * D + lane];
    a0 += e0 + n0; a1 += e1 + n1;
  }
  if (i < c) {
    long long q = p[i];
    a2 += __builtin_nontemporal_load(edge + (size_t)(unsigned)(q) * D + lane)
        + node[(size_t)(unsigned)(q >> 32) * D + lane];
  }
  float acc = (a0 + a1) + (a2 + a3);
  float inv = (c > 0) ? (1.0f / (float)c) : 0.0f;
  float hv = fmaf(1.0f + epsp[0], node[(size_t)wid * D + lane], acc * inv);
  h[(size_t)wid * D + lane] = hv;
}

// ---------------- GEMM1 + bias + BN1 stats (LDS-tiled) ----------------
// tile: 64 rows x 128 cols, 256 threads, thread = 8 rows x 4 cols
__global__ __launch_bounds__(256) void k_gemm1(
    const float* __restrict__ h, const float* __restrict__ W1,
    const float* __restrict__ b1, float* __restrict__ h1,
    float* __restrict__ sum1, float* __restrict__ sq1, int N)
{
  __shared__ float sW[D][H];      // 32 KB  W1 copy [k][c]
  __shared__ float sX[64][D];     // 16 KB  h tile  [r][k]
  __shared__ float sSum[H], sSq[H];

  const int t = threadIdx.x;
  const int row0 = blockIdx.x * 64;

  // stage W1: 8192 floats, 8 float4/thread, contiguous
  {
    const float4* gW = (const float4*)W1;
    float4* sWv = (float4*)&sW[0][0];
#pragma unroll
    for (int q = 0; q < 8; ++q) sWv[q * 256 + t] = gW[q * 256 + t];
  }
  // stage h tile: 4096 floats, 4 float4/thread; zero-pad tail rows
  {
    float4* sXv = (float4*)&sX[0][0];
#pragma unroll
    for (int q = 0; q < 4; ++q) {
      int idx = q * 256 + t;          // float4 idx: row = idx>>4, col4 = idx&15
      int r = idx >> 4;
      int gr = row0 + r;
      float4 v = make_float4(0.f, 0.f, 0.f, 0.f);
      if (gr < N) v = *(const float4*)(h + (size_t)gr * D + (idx & 15) * 4);
      sXv[idx] = v;
    }
  }
  if (t < H) { sSum[t] = 0.f; sSq[t] = 0.f; }
  __syncthreads();

  const int rg = t >> 5;   // 0..7   (8 rows each)
  const int cg = t & 31;   // 0..31  (4 cols each)
  const int r0 = rg * 8;
  const int c0 = cg * 4;

  float acc[8][4];
#pragma unroll
  for (int i = 0; i < 8; ++i)
#pragma unroll
    for (int j = 0; j < 4; ++j) acc[i][j] = 0.f;

  for (int k = 0; k < D; k += 4) {
    float4 xv[8], wv[4];
#pragma unroll
    for (int i = 0; i < 8; ++i) xv[i] = *(const float4*)&sX[r0 + i][k];
#pragma unroll
    for (int kk = 0; kk < 4; ++kk) wv[kk] = *(const float4*)&sW[k + kk][c0];
#pragma unroll
    for (int kk = 0; kk < 4; ++kk) {
      const float* wp = (const float*)&wv[kk];
#pragma unroll
      for (int i = 0; i < 8; ++i) {
        const float xs = ((const float*)&xv[i])[kk];
        acc[i][0] = fmaf(xs, wp[0], acc[i][0]);
        acc[i][1] = fmaf(xs, wp[1], acc[i][1]);
        acc[i][2] = fmaf(xs, wp[2], acc[i][2]);
        acc[i][3] = fmaf(xs, wp[3], acc[i][3]);
      }
    }
  }

  const float4 bv = *(const float4*)(b1 + c0);
  float ls0 = 0.f, ls1 = 0.f, ls2 = 0.f, ls3 = 0.f;
  float lq0 = 0.f, lq1 = 0.f, lq2 = 0.f, lq3 = 0.f;
#pragma unroll
  for (int i = 0; i < 8; ++i) {
    int gr = row0 + r0 + i;
    if (gr < N) {
      float o0 = acc[i][0] + bv.x, o1 = acc[i][1] + bv.y;
      float o2 = acc[i][2] + bv.z, o3 = acc[i][3] + bv.w;
      *(float4*)(h1 + (size_t)gr * H + c0) = make_float4(o0, o1, o2, o3);
      ls0 += o0; lq0 += o0 * o0;
      ls1 += o1; lq1 += o1 * o1;
      ls2 += o2; lq2 += o2 * o2;
      ls3 += o3; lq3 += o3 * o3;
    }
  }
  // combine the two row-groups sharing this wave, then LDS-reduce
  ls0 += __shfl_xor(ls0, 32, 64); lq0 += __shfl_xor(lq0, 32, 64);
  ls1 += __shfl_xor(ls1, 32, 64); lq1 += __shfl_xor(lq1, 32, 64);
  ls2 += __shfl_xor(ls2, 32, 64); lq2 += __shfl_xor(lq2, 32, 64);
  ls3 += __shfl_xor(ls3, 32, 64); lq3 += __shfl_xor(lq3, 32, 64);
  if (!(t & 32)) {
    atomicAdd(&sSum[c0 + 0], ls0); atomicAdd(&sSq[c0 + 0], lq0);
    atomicAdd(&sSum[c0 + 1], ls1); atomicAdd(&sSq[c0 + 1], lq1);
    atomicAdd(&sSum[c0 + 2], ls2); atomicAdd(&sSq[c0 + 2], lq2);
    atomicAdd(&sSum[c0 + 3], ls3); atomicAdd(&sSq[c0 + 3], lq3);
  }
  __syncthreads();
  if (t < H) { atomicAdd(sum1 + t, sSum[t]); atomicAdd(sq1 + t, sSq[t]); }
}

// ---------------- BN finalize -----------------------
__global__ void k_finalize(const float* __restrict__ sum, const float* __restrict__ sq,
                           const float* __restrict__ gamma, const float* __restrict__ beta,
                           float* __restrict__ scale, float* __restrict__ shift,
                           int C, float invN)
{
  int k = threadIdx.x;
  if (k < C) {
    float m = sum[k] * invN;
    float var = fmaf(-m, m, sq[k] * invN);
    float sc = gamma[k] * rsqrtf(var + 1e-5f);
    scale[k] = sc;
    shift[k] = fmaf(-m, sc, beta[k]);
  }
}

// ---------------- BN1+ReLU + GEMM2 + bias + BN2 stats (LDS-tiled) -----------
// tile: 64 rows x 64 cols, 256 threads, thread = 4 rows x 4 cols
__global__ __launch_bounds__(256) void k_gemm2(
    const float* __restrict__ h1, const float* __restrict__ scale1,
    const float* __restrict__ shift1, const float* __restrict__ W2,
    const float* __restrict__ b2, float* __restrict__ out,
    float* __restrict__ sum2, float* __restrict__ sq2, int N)
{
  __shared__ float sW[H][D];          // 32 KB  W2 copy [k][c]
  __shared__ float sX[64][H + 4];     // 33 KB  relu(bn1(h1)) tile, padded
  __shared__ float sSum[D], sSq[D];

  const int t = threadIdx.x;
  const int row0 = blockIdx.x * 64;

  // stage W2: 8192 floats, 8 float4/thread
  {
    const float4* gW = (const float4*)W2;
    float4* sWv = (float4*)&sW[0][0];
#pragma unroll
    for (int q = 0; q < 8; ++q) sWv[q * 256 + t] = gW[q * 256 + t];
  }
  // stage A tile with BN1+ReLU fused: 8192 floats, 8 float4/thread
#pragma unroll
  for (int q = 0; q < 8; ++q) {
    int idx = q * 256 + t;             // float4 idx: row = idx>>5, k4 = (idx&31)*4
    int r = idx >> 5;
    int k4 = (idx & 31) * 4;
    int gr = row0 + r;
    float4 x = make_float4(0.f, 0.f, 0.f, 0.f);
    if (gr < N) {
      float4 v  = *(const float4*)(h1 + (size_t)gr * H + k4);
      float4 sc = *(const float4*)(scale1 + k4);
      float4 sh = *(const float4*)(shift1 + k4);
      x.x = fmaxf(fmaf(v.x, sc.x, sh.x), 0.f);
      x.y = fmaxf(fmaf(v.y, sc.y, sh.y), 0.f);
      x.z = fmaxf(fmaf(v.z, sc.z, sh.z), 0.f);
      x.w = fmaxf(fmaf(v.w, sc.w, sh.w), 0.f);
    }
    *(float4*)&sX[r][k4] = x;
  }
  if (t < D) { sSum[t] = 0.f; sSq[t] = 0.f; }
  __syncthreads();

  const int rg = t >> 4;   // 0..15  (4 rows each)
  const int cg = t & 15;   // 0..15  (4 cols each)
  const int r0 = rg * 4;
  const int c0 = cg * 4;

  float acc[4][4];
#pragma unroll
  for (int i = 0; i < 4; ++i)
#pragma unroll
    for (int j = 0; j < 4; ++j) acc[i][j] = 0.f;

  for (int k = 0; k < H; k += 4) {
    float4 xv[4], wv[4];
#pragma unroll
    for (int i = 0; i < 4; ++i) xv[i] = *(const float4*)&sX[r0 + i][k];
#pragma unroll
    for (int kk = 0; kk < 4; ++kk) wv[kk] = *(const float4*)&sW[k + kk][c0];
#pragma unroll
    for (int kk = 0; kk < 4; ++kk) {
      const float* wp = (const float*)&wv[kk];
#pragma unroll
      for (int i = 0; i < 4; ++i) {
        const float xs = ((const float*)&xv[i])[kk];
        acc[i][0] = fmaf(xs, wp[0], acc[i][0]);
        acc[i][1] = fmaf(xs, wp[1], acc[i][1]);
        acc[i][2] = fmaf(xs, wp[2], acc[i][2]);
        acc[i][3] = fmaf(xs, wp[3], acc[i][3]);
      }
    }
  }

  const float4 bv = *(const float4*)(b2 + c0);
  float ls[4] = {0.f, 0.f, 0.f, 0.f};
  float lq[4] = {0.f, 0.f, 0.f, 0.f};
#pragma unroll
  for (int i = 0; i < 4; ++i) {
    int gr = row0 + r0 + i;
    if (gr < N) {
      float o0 = acc[i][0] + bv.x, o1 = acc[i][1] + bv.y;
      float o2 = acc[i][2] + bv.z, o3 = acc[i][3] + bv.w;
      *(float4*)(out + (size_t)gr * D + c0) = make_float4(o0, o1, o2, o3);
      ls[0] += o0; lq[0] += o0 * o0;
      ls[1] += o1; lq[1] += o1 * o1;
      ls[2] += o2; lq[2] += o2 * o2;
      ls[3] += o3; lq[3] += o3 * o3;
    }
  }
#pragma unroll
  for (int j = 0; j < 4; ++j) {
    ls[j] += __shfl_xor(ls[j], 16, 64); lq[j] += __shfl_xor(lq[j], 16, 64);
    ls[j] += __shfl_xor(ls[j], 32, 64); lq[j] += __shfl_xor(lq[j], 32, 64);
  }
  if ((t & 48) == 0) {
#pragma unroll
    for (int j = 0; j < 4; ++j) {
      atomicAdd(&sSum[c0 + j], ls[j]);
      atomicAdd(&sSq[c0 + j], lq[j]);
    }
  }
  __syncthreads();
  if (t < D) { atomicAdd(sum2 + t, sSum[t]); atomicAdd(sq2 + t, sSq[t]); }
}

// ---------------- final BN2 + ReLU (in-place on d_out) ------------
__global__ __launch_bounds__(256) void k_bnrelu(
    float* __restrict__ out, const float* __restrict__ scale2,
    const float* __restrict__ shift2, size_t n4)
{
  size_t idx = (size_t)blockIdx.x * 256 + threadIdx.x;
  if (idx >= n4) return;
  int k = (int)((idx * 4) & (D - 1));
  float4 v = *(float4*)(out + idx * 4);
  v.x = fmaxf(fmaf(v.x, scale2[k + 0], shift2[k + 0]), 0.0f);
  v.y = fmaxf(fmaf(v.y, scale2[k + 1], shift2[k + 1]), 0.0f);
  v.z = fmaxf(fmaf(v.z, scale2[k + 2], shift2[k + 2]), 0.0f);
  v.w = fmaxf(fmaf(v.w, scale2[k + 3], shift2[k + 3]), 0.0f);
  *(float4*)(out + idx * 4) = v;
}

extern "C" void kernel_launch(void* const* d_in, const int* in_sizes, int n_in,
                              void* d_out, int out_size, void* d_ws, size_t ws_size,
                              hipStream_t stream)
{
  const float* node   = (const float*)d_in[0];
  const float* edge   = (const float*)d_in[1];
  const int*   src    = (const int*)d_in[2];
  const int*   dst    = (const int*)d_in[3];
  const float* eps    = (const float*)d_in[4];
  const float* W1     = (const float*)d_in[5];
  const float* b1     = (const float*)d_in[6];
  const float* gamma1 = (const float*)d_in[7];
  const float* beta1  = (const float*)d_in[8];
  const float* W2     = (const float*)d_in[9];
  const float* b2     = (const float*)d_in[10];
  const float* gamma2 = (const float*)d_in[11];
  const float* beta2  = (const float*)d_in[12];
  float* out = (float*)d_out;

  const int N = in_sizes[0] / D;
  const int E = in_sizes[2];

  // workspace layout in 4-byte words:
  //   0: sum1(H) 128: sq1(H) 256: sum2(D) 320: sq2(D)
  //   384: scale1(H) 512: shift1(H) 640: scale2(D) 704: shift2(D)
  //   768: total(1) [pad to 832]
  //   832: cnt(N)  832+N: offs(N)  832+2N: cursor(N)
  //   832+3N: h(N*D)
  //   832+3N+N*D: csr(2E) aliased with h1(N*H)  [lifetimes disjoint]
  char* base = (char*)d_ws;
  float* sum1   = (float*)base;
  float* sq1    = sum1 + H;
  float* sum2   = sq1 + H;
  float* sq2    = sum2 + D;
  float* scale1 = sq2 + D;
  float* shift1 = scale1 + H;
  float* scale2 = shift1 + H;
  float* shift2 = scale2 + D;
  int*   total  = (int*)(shift2 + D);          // word 768
  int*   cnt    = (int*)base + 832;
  int*   offs   = cnt + N;
  int*   cursor = offs + N;
  float* h      = (float*)(cursor + N);
  int2*  csr    = (int2*)(h + (size_t)N * D);
  float* h1     = (float*)csr;

  // zero: stats (0..384), total (768), cnt — one contiguous memset of the
  // first 832+N words covers all of them (scale/shift are write-before-read)
  hipMemsetAsync(d_ws, 0, (size_t)(832 + N) * sizeof(int), stream);

  int ebn = (E + 255) / 256;
  int nbn = (N + 255) / 256;
  k_hist<<<ebn, 256, 0, stream>>>(dst, cnt, E);
  k_alloc<<<nbn, 256, 0, stream>>>(cnt, offs, cursor, total, N);
  k_bin<<<ebn, 256, 0, stream>>>(src, dst, cursor, csr, E);
  k_agg<<<(N * 64 + 255) / 256, 256, 0, stream>>>(node, edge, csr, offs, cnt, eps, h, N);

  int gtile = (N + 63) / 64;
  k_gemm1<<<gtile, 256, 0, stream>>>(h, W1, b1, h1, sum1, sq1, N);
  k_finalize<<<1, H, 0, stream>>>(sum1, sq1, gamma1, beta1, scale1, shift1, H, 1.0f / (float)N);
  k_gemm2<<<gtile, 256, 0, stream>>>(h1, scale1, shift1, W2, b2, out, sum2, sq2, N);
  k_finalize<<<1, D, 0, stream>>>(sum2, sq2, gamma2, beta2, scale2, shift2, D, 1.0f / (float)N);

  size_t n4 = (size_t)N * D / 4;
  k_bnrelu<<<(int)((n4 + 255) / 256), 256, 0, stream>>>(out, scale2, shift2, n4);
}